// Round 11
// baseline (398.548 us; speedup 1.0000x reference)
//
#include <hip/hip_runtime.h>
#include <hip/hip_bf16.h>
#include <stdint.h>

// FusedLinearCrossEntropyLoss on MI355X (gfx950)
// loss = mean_i( logsumexp_j(x_i . w_j + b_j) - (x_i . w_t(i) + b_t(i)) )
//
// R15: gemm grid-order swap + occupancy 4. Loop body untouched (R12-proven).
//   Diagnosis: gemm FETCH=130.6MB vs 37MB unique fp8 => 3.5x HBM re-fetch.
//   With bx fast-varying, ~8 panels in flight each need ALL of X (4MB) ->
//   per-XCD set 5MB > 4MB L2 -> X re-fetched per panel (250*4MB/8 ~ 125MB,
//   matches). 900cy HBM misses = the exposed-latency capping MfmaUtil at 37%.
//   Fix (a): by fast-varying -> 250 consecutive blocks share one 128KB X-slab
//   (L2-resident); W streams, L3-hits for later bx groups. Ideal fetch ~40MB.
//   Fix (b): launch_bounds(256,4): VGPR 56 + AGPR 64 = 120 <= 128 -> 4
//   waves/SIMD (R12 bound capped at 3). Tripwire: WRITE_SIZE >> 4MB = spill.
//   Cast/row_reduce/finalize unchanged from R14 (cast proven non-critical:
//   two radically different casts gave identical totals).
//
// Chunk layout (contiguous 32B/lane): chunk c = R*16 + g. lane l, byte b:
//   data[c*2048 + l*32 + b] = M[R*32 + (l&31)][g*64 + (l>>5)*32 + b]

typedef float f16v __attribute__((ext_vector_type(16)));
typedef int v8i __attribute__((ext_vector_type(8)));
typedef int v4i __attribute__((ext_vector_type(4)));

__device__ __forceinline__ unsigned pk_fp8(float4 v) {
  int w = 0;
  w = __builtin_amdgcn_cvt_pk_fp8_f32(v.x, v.y, w, false);  // bytes 0,1
  w = __builtin_amdgcn_cvt_pk_fp8_f32(v.z, v.w, w, true);   // bytes 2,3
  return (unsigned)w;
}

// fp32 [N x 1024] -> fp8 fragment chunks via LDS staging.
// Block = one 32-row stripe. Coalesced row reads -> fp8 in fragment layout
// in LDS -> linear coalesced dump. (R14, verified absmax 0.)
__global__ __launch_bounds__(256) void cast_stage_k(const float* __restrict__ inW,
                                                    char* __restrict__ outW,
                                                    const float* __restrict__ inX,
                                                    char* __restrict__ outX,
                                                    int sW, int sTot) {
  __shared__ unsigned lds[8192];  // 32 KB
  int s = blockIdx.x;
  const float* in;
  char* out;
  if (s < sW) { in = inW; out = outW; }
  else        { in = inX; out = outX; s -= sW; }
  const int t = threadIdx.x;
  const float4* src = (const float4*)in + (long)s * 8192 + t;
  const int u0 = ((t >> 3) << 8) + (t & 7);
#pragma unroll 4
  for (int r = 0; r < 32; ++r) lds[u0 + r * 8] = pk_fp8(src[r * 256]);
  __syncthreads();
  const uint4* lv = (const uint4*)lds;
  uint4* dst = (uint4*)(out + (long)s * 32768);
#pragma unroll
  for (int p = 0; p < 8; ++p) dst[p * 256 + t] = lv[p * 256 + t];
}

// Load one 32B/lane fragment (two adjacent dwordx4 -> v8i).
__device__ __forceinline__ v8i ldfrag(const char* p) {
  const v4i* q = (const v4i*)p;
  v4i lo = q[0];
  v4i hi = q[1];
  return __builtin_shufflevector(lo, hi, 0, 1, 2, 3, 4, 5, 6, 7);
}

#define MFMA1(A, B, C) \
  __builtin_amdgcn_mfma_scale_f32_32x32x64_f8f6f4(A, B, C, 0, 0, 0, 127, 0, 127)

// 128x128 block tile, 4 waves in 2x2; each wave 64x64 via 2x2 of 32x32x64.
// No LDS staging, no barriers in the K-loop, one operand set live.
// Grid: by = blockIdx.x (FAST: panels), bx = blockIdx.y (row slabs).
__global__ __launch_bounds__(256, 4)
void gemm_sumexp(const char* __restrict__ Xf, const char* __restrict__ Wf,
                 const float* __restrict__ bias, float* __restrict__ partials,
                 int H, int BT) {
  __shared__ float rowsum[2][128];

  const int tid = threadIdx.x;
  const int w = tid >> 6, lane = tid & 63;
  const int wr = w >> 1, wc = w & 1;
  const int l32 = lane & 31, kh = lane >> 5;

  const int by = blockIdx.x;   // column panels fast-varying (X slab L2-resident)
  const int bx = blockIdx.y;
  const int m0 = bx * 128, n0 = by * 128;

  const int Rb = bx * 4 + wr * 2;   // A 32-row block base
  const int Nb = by * 4 + wc * 2;   // B 32-row block base

  const char* pA0 = Xf + (long)(Rb + 0) * 32768 + lane * 32;
  const char* pA1 = Xf + (long)(Rb + 1) * 32768 + lane * 32;
  const char* pB0 = Wf + (long)(Nb + 0) * 32768 + lane * 32;
  const char* pB1 = Wf + (long)(Nb + 1) * 32768 + lane * 32;

  f16v acc[2][2];
#pragma unroll
  for (int mi = 0; mi < 2; mi++)
#pragma unroll
    for (int ni = 0; ni < 2; ni++)
#pragma unroll
      for (int r = 0; r < 16; r++) acc[mi][ni][r] = 0.f;

  const int nG = H >> 6;  // 16 k-groups of 64
#pragma unroll 4
  for (int g = 0; g < nG; g++) {
    v8i a0 = ldfrag(pA0); pA0 += 2048;
    v8i a1 = ldfrag(pA1); pA1 += 2048;
    v8i b0 = ldfrag(pB0); pB0 += 2048;
    v8i b1 = ldfrag(pB1); pB1 += 2048;
    acc[0][0] = MFMA1(a0, b0, acc[0][0]);
    acc[0][1] = MFMA1(a0, b1, acc[0][1]);
    acc[1][0] = MFMA1(a1, b0, acc[1][0]);
    acc[1][1] = MFMA1(a1, b1, acc[1][1]);
  }

  // ---- epilogue: per-row sum of exp(logit + bias) ----
  // C/D 32x32 layout: col = lane&31, row = (reg&3) + 8*(reg>>2) + 4*(lane>>5)
  float bv[2];
  bv[0] = bias[n0 + wc * 64 + l32];
  bv[1] = bias[n0 + wc * 64 + 32 + l32];

#pragma unroll
  for (int mi = 0; mi < 2; mi++) {
    float p[16];
#pragma unroll
    for (int r = 0; r < 16; r++) p[r] = 0.f;
#pragma unroll
    for (int ni = 0; ni < 2; ni++)
#pragma unroll
      for (int r = 0; r < 16; r++) p[r] += __expf(acc[mi][ni][r] + bv[ni]);
    // reduce across the 32 columns (lanes within each 32-group)
#pragma unroll
    for (int off = 1; off < 32; off <<= 1)
#pragma unroll
      for (int r = 0; r < 16; r++) p[r] += __shfl_xor(p[r], off, 32);
    if (l32 == 0) {
#pragma unroll
      for (int r = 0; r < 16; r++)
        rowsum[wc][wr * 64 + mi * 32 + (r & 3) + 8 * (r >> 2) + 4 * kh] = p[r];
    }
  }
  __syncthreads();
  if (tid < 128)
    partials[(long)by * BT + m0 + tid] = rowsum[0][tid] + rowsum[1][tid];
}

// Fused per-row finish: S = sum of panel partials; x_y = x[row].W[t] + b[t]
// (exact fp32); pr = log(S) - x_y. One wave per row.
__global__ __launch_bounds__(256)
void row_reduce(const float* __restrict__ partials, const float* __restrict__ x,
                const float* __restrict__ wt, const float* __restrict__ bias,
                const int* __restrict__ tgt, float* __restrict__ bsum,
                float* __restrict__ bcnt, int BT, int nCB, int H, int V) {
  const int w = threadIdx.x >> 6, lane = threadIdx.x & 63;
  const int row = blockIdx.x * 4 + w;
  float S = 0.f;
  for (int b = lane; b < nCB; b += 64) S += partials[(long)b * BT + row];
  const int t = tgt[row];
  const int st = min(max(t, 0), V - 1);
  const float4* xr = (const float4*)(x + (long)row * H);
  const float4* wr = (const float4*)(wt + (long)st * H);
  float d = 0.f;
  const int n4 = H >> 2;
  for (int i = lane; i < n4; i += 64) {
    float4 a = xr[i], b = wr[i];
    d += a.x * b.x + a.y * b.y + a.z * b.z + a.w * b.w;
  }
  for (int off = 32; off; off >>= 1) {
    S += __shfl_down(S, off, 64);
    d += __shfl_down(d, off, 64);
  }
  __shared__ float sp[4], sc[4];
  if (lane == 0) {
    bool valid = (t != -100);
    sp[w] = valid ? (logf(S) - (d + bias[st])) : 0.f;
    sc[w] = valid ? 1.f : 0.f;
  }
  __syncthreads();
  if (threadIdx.x == 0) {
    bsum[blockIdx.x] = sp[0] + sp[1] + sp[2] + sp[3];
    bcnt[blockIdx.x] = sc[0] + sc[1] + sc[2] + sc[3];
  }
}

__global__ void finalize(const float* __restrict__ bsum, const float* __restrict__ bcnt,
                         float* __restrict__ out, int nb) {
  float s = 0.f, c = 0.f;
  for (int i = threadIdx.x; i < nb; i += 64) { s += bsum[i]; c += bcnt[i]; }
  for (int off = 32; off; off >>= 1) {
    s += __shfl_down(s, off, 64);
    c += __shfl_down(c, off, 64);
  }
  if (threadIdx.x == 0) out[0] = s / c;
}

extern "C" void kernel_launch(void* const* d_in, const int* in_sizes, int n_in,
                              void* d_out, int out_size, void* d_ws, size_t ws_size,
                              hipStream_t stream) {
  const float* x = (const float*)d_in[0];
  const int* tgt = (const int*)d_in[1];
  const float* w = (const float*)d_in[2];
  const float* bias = (const float*)d_in[3];
  float* out = (float*)d_out;

  const int BT = in_sizes[1];            // 4096
  const int V = in_sizes[3];             // 32000
  const int H = in_sizes[0] / BT;        // 1024
  const int nCB = V / 128;               // 250 column panels

  char* ws = (char*)d_ws;
  const long wb_bytes = (long)V * H;     // fp8: 1 B/elem
  const long xb_bytes = (long)BT * H;
  char* Wf = ws;
  char* Xf = ws + wb_bytes;
  float* partials = (float*)(ws + wb_bytes + xb_bytes);
  float* bsum = partials + (long)nCB * BT;
  float* bcnt = bsum + (BT / 4);

  const int sW = V / 32;                 // 1000 W stripes
  const int sTot = sW + BT / 32;         // + 128 X stripes
  cast_stage_k<<<sTot, 256, 0, stream>>>(w, Wf, x, Xf, sW, sTot);
  dim3 grid(nCB, BT / 128);              // by fast-varying
  gemm_sumexp<<<grid, 256, 0, stream>>>(Xf, Wf, bias, partials, H, BT);
  row_reduce<<<BT / 4, 256, 0, stream>>>(partials, x, w, bias, tgt, bsum, bcnt,
                                         BT, nCB, H, V);
  finalize<<<1, 64, 0, stream>>>(bsum, bcnt, out, BT / 4);
}